// Round 18
// baseline (320.738 us; speedup 1.0000x reference)
//
#include <hip/hip_runtime.h>
#include <hip/hip_fp16.h>

// HyenaFilter = implicit-filter MLP (tiny) + FFT convolution.
// fftconv == causal linear conv; bias folded into k[0].
// R18: overlap-add with F=8192 LDS-resident FFTs (64KB -> 2 blocks/CU,
//   2x occupancy; R16/17's 16384-FFT forced 1 block/CU and left barriers
//   unhidden). Per channel: y[0:4096)=invA lo; y[4096:)=invA hi + invB lo,
//   A=K0*ZA, B=K0*ZB + K1*ZA. C=K1*ZA kept in 16 named regs; A-hi stashed
//   into final y-hi addresses, same-thread += later. kfft pairs the two
//   REAL k-chunks of one channel as one complex 8192-FFT, Hermitian unpack
//   with digit map (8,8,8,8,2). MODE1 fallback = validated 16384 path.

#define DIMC  768
#define BANDS 16
#define FO    64
#define LSEQ  8192
#define NF    16384
#define PI_F  3.14159265358979323846f
#define RSQ2  0.70710678118654752f

typedef float v2f __attribute__((ext_vector_type(2)));

#define REP32(M) M(0) M(1) M(2) M(3) M(4) M(5) M(6) M(7) M(8) M(9) M(10) M(11) \
    M(12) M(13) M(14) M(15) M(16) M(17) M(18) M(19) M(20) M(21) M(22) M(23) \
    M(24) M(25) M(26) M(27) M(28) M(29) M(30) M(31)

__device__ __forceinline__ int swz(int i) { return i ^ ((i >> 4) & 15); }

__device__ __forceinline__ v2f mni(v2f v) { v2f t = v.yx; t.y = -t.y; return t; } // -i*v
__device__ __forceinline__ v2f pli(v2f v) { v2f t = v.yx; t.x = -t.x; return t; } // +i*v
__device__ __forceinline__ v2f cmulm(v2f x, float c, float s) {   // x*(c - i s)
    v2f t = x.yx; t.y = -t.y;
    return x * c + t * s;
}
__device__ __forceinline__ v2f cmulp(v2f x, float c, float s) {   // x*(c + i s)
    v2f t = x.yx; t.x = -t.x;
    return x * c + t * s;
}
// complex mult by half2-stored K: z*k
__device__ __forceinline__ v2f kmul(__half2 kh, v2f z) {
    float2 kk = __half22float2(kh);
    v2f k = {kk.x, kk.y};
    return k * z.x + pli(k) * z.y;
}

#define TWCHAIN7(TH) \
    float c1=__cosf(TH), s1=__sinf(TH); \
    float c2=c1*c1-s1*s1, s2=2.f*c1*s1; \
    float c3=c1*c2-s1*s2, s3=s1*c2+c1*s2; \
    float c4=c2*c2-s2*s2, s4=2.f*c2*s2; \
    float c5=c2*c3-s2*s3, s5=s2*c3+c2*s3; \
    float c6=c3*c3-s3*s3, s6=2.f*c3*s3; \
    float c7=c3*c4-s3*s4, s7=s3*c4+c3*s4

// ---- radix-8 fwd DIF stage; MIT butterflies/thread (N = MIT*8192) --------
template<int SH, int MIT>
__device__ __forceinline__ void fwd8s(v2f* L, int t)
{
    __syncthreads();
    const int S = 1 << SH;
#pragma unroll 1
    for (int m = 0; m < MIT; ++m) {
        int b = t + (m << 10);
        int q = b & (S - 1);
        int p = ((b >> SH) << (SH + 3)) + q;
        v2f u0 = L[swz(p)];
        v2f u1 = L[swz(p + S)];
        v2f u2 = L[swz(p + 2 * S)];
        v2f u3 = L[swz(p + 3 * S)];
        v2f u4 = L[swz(p + 4 * S)];
        v2f u5 = L[swz(p + 5 * S)];
        v2f u6 = L[swz(p + 6 * S)];
        v2f u7 = L[swz(p + 7 * S)];
        v2f a0 = u0 + u4, b0 = u0 - u4;
        v2f a1 = u1 + u5, b1 = u1 - u5;
        v2f a2 = u2 + u6, b2 = u2 - u6;
        v2f a3 = u3 + u7, b3 = u3 - u7;
        v2f e0 = a0 + a2, e1 = a0 - a2;
        v2f f0 = a1 + a3, f1 = a1 - a3;
        v2f y0 = e0 + f0, y4 = e0 - f0;
        v2f nf1 = mni(f1);
        v2f y2 = e1 + nf1, y6 = e1 - nf1;
        v2f v1 = cmulm(b1,  RSQ2, RSQ2);
        v2f v2 = mni(b2);
        v2f v3 = cmulm(b3, -RSQ2, RSQ2);
        v2f g0 = b0 + v2, g1 = b0 - v2;
        v2f h0 = v1 + v3, h1 = v1 - v3;
        v2f y1 = g0 + h0, y5 = g0 - h0;
        v2f nh1 = mni(h1);
        v2f y3 = g1 + nh1, y7 = g1 - nh1;
        float th = (float)q * (PI_F / (4.0f * (float)S));
        TWCHAIN7(th);
        L[swz(p)]         = y0;
        L[swz(p + S)]     = cmulm(y1, c1, s1);
        L[swz(p + 2 * S)] = cmulm(y2, c2, s2);
        L[swz(p + 3 * S)] = cmulm(y3, c3, s3);
        L[swz(p + 4 * S)] = cmulm(y4, c4, s4);
        L[swz(p + 5 * S)] = cmulm(y5, c5, s5);
        L[swz(p + 6 * S)] = cmulm(y6, c6, s6);
        L[swz(p + 7 * S)] = cmulm(y7, c7, s7);
    }
}

// first fwd stage, zero-padded input (u4..u7 = 0); strides NS = N/8
template<int NS>
__device__ __forceinline__ void fwd8_first(v2f* L, int q,
                                           v2f u0, v2f u1, v2f u2, v2f u3)
{
    v2f e0 = u0 + u2, e1 = u0 - u2;
    v2f f0 = u1 + u3, f1 = u1 - u3;
    v2f y0 = e0 + f0, y4 = e0 - f0;
    v2f nf1 = mni(f1);
    v2f y2 = e1 + nf1, y6 = e1 - nf1;
    v2f v1 = cmulm(u1,  RSQ2, RSQ2);
    v2f v2 = mni(u2);
    v2f v3 = cmulm(u3, -RSQ2, RSQ2);
    v2f g0 = u0 + v2, g1 = u0 - v2;
    v2f h0 = v1 + v3, h1 = v1 - v3;
    v2f y1 = g0 + h0, y5 = g0 - h0;
    v2f nh1 = mni(h1);
    v2f y3 = g1 + nh1, y7 = g1 - nh1;
    float th = (float)q * (PI_F / (4.0f * (float)NS));
    TWCHAIN7(th);
    L[swz(q)]          = y0;
    L[swz(q + NS)]     = cmulm(y1, c1, s1);
    L[swz(q + 2 * NS)] = cmulm(y2, c2, s2);
    L[swz(q + 3 * NS)] = cmulm(y3, c3, s3);
    L[swz(q + 4 * NS)] = cmulm(y4, c4, s4);
    L[swz(q + 5 * NS)] = cmulm(y5, c5, s5);
    L[swz(q + 6 * NS)] = cmulm(y6, c6, s6);
    L[swz(q + 7 * NS)] = cmulm(y7, c7, s7);
}

// ---- radix-8 inv DIT stage ------------------------------------------------
template<int SH, int MIT>
__device__ __forceinline__ void inv8s(v2f* L, int t)
{
    __syncthreads();
    const int S = 1 << SH;
#pragma unroll 1
    for (int m = 0; m < MIT; ++m) {
        int b = t + (m << 10);
        int q = b & (S - 1);
        int p = ((b >> SH) << (SH + 3)) + q;
        float th = (float)q * (PI_F / (4.0f * (float)S));
        TWCHAIN7(th);
        v2f y0 = L[swz(p)];
        v2f y1 = cmulp(L[swz(p + S)],     c1, s1);
        v2f y2 = cmulp(L[swz(p + 2*S)],   c2, s2);
        v2f y3 = cmulp(L[swz(p + 3*S)],   c3, s3);
        v2f y4 = cmulp(L[swz(p + 4*S)],   c4, s4);
        v2f y5 = cmulp(L[swz(p + 5*S)],   c5, s5);
        v2f y6 = cmulp(L[swz(p + 6*S)],   c6, s6);
        v2f y7 = cmulp(L[swz(p + 7*S)],   c7, s7);
        v2f E0 = y0 + y4, F0 = y0 - y4;
        v2f E1 = y2 + y6, F1 = pli(y2 - y6);
        v2f a0 = E0 + E1, a2 = E0 - E1;
        v2f a1 = F0 + F1, a3 = F0 - F1;
        v2f G0 = y1 + y5, H0 = y1 - y5;
        v2f G1 = y3 + y7, H1 = pli(y3 - y7);
        v2f w0 = G0 + G1, w2 = G0 - G1;
        v2f w1 = H0 + H1, w3 = H0 - H1;
        v2f b0 = w0;
        v2f b1 = cmulp(w1,  RSQ2, RSQ2);
        v2f b2 = pli(w2);
        v2f b3 = cmulp(w3, -RSQ2, RSQ2);
        L[swz(p)]         = a0 + b0;
        L[swz(p + S)]     = a1 + b1;
        L[swz(p + 2 * S)] = a2 + b2;
        L[swz(p + 3 * S)] = a3 + b3;
        L[swz(p + 4 * S)] = a0 - b0;
        L[swz(p + 5 * S)] = a1 - b1;
        L[swz(p + 6 * S)] = a2 - b2;
        L[swz(p + 7 * S)] = a3 - b3;
    }
}

// trivial-twiddle radix-4 (S=1) fwd / inv (packed) — used by MODE1 path
__device__ __forceinline__ void bf4f0(v2f& a, v2f& b, v2f& c, v2f& d)
{
    v2f A = a + c, B = a - c, C = b + d, D = mni(b - d);
    a = A + C; b = B + D; c = A - C; d = B - D;
}
__device__ __forceinline__ void bf4i0(v2f& a, v2f& b, v2f& c, v2f& d)
{
    v2f e0 = a + c, e1 = a - c, f0 = b + d, f1 = pli(b - d);
    a = e0 + f0; b = e1 + f1; c = e0 - f0; d = e1 - f1;
}

// ---------- Kernel 1: MLP hidden states h2[FO][LSEQ] ----------------------
__global__ void hidden_kernel(const float* __restrict__ W0, const float* __restrict__ b0,
                              const float* __restrict__ W1, const float* __restrict__ b1,
                              const float* __restrict__ W2, const float* __restrict__ b2,
                              const float* __restrict__ freq, float* __restrict__ hws)
{
    const int lane = threadIdx.x & 63;
    const int p = blockIdx.x * (blockDim.x >> 6) + (threadIdx.x >> 6);
    if (p >= LSEQ) return;
    const float tt = (float)p / (float)(LSEQ - 1);
    const float w  = 6.283185307179586f * (float)p / (float)LSEQ;

    float acc = b0[lane] + tt * W0[lane];
#pragma unroll
    for (int j = 0; j < BANDS; ++j) {
        float f = 1e-4f + (float)j * ((15.0f - 1e-4f) / 15.0f);
        float a = f * w;
        acc += __cosf(a)  * W0[(1 + j) * FO + lane];
        acc += -__sinf(a) * W0[(1 + BANDS + j) * FO + lane];
    }
    float h = __sinf(freq[lane] * acc);

    acc = b1[lane];
#pragma unroll
    for (int e = 0; e < FO; ++e) acc += __shfl(h, e) * W1[e * FO + lane];
    float h1 = __sinf(freq[lane] * acc);

    acc = b2[lane];
#pragma unroll
    for (int e = 0; e < FO; ++e) acc += __shfl(h1, e) * W2[e * FO + lane];
    float h2 = __sinf(freq[lane] * acc);

    hws[lane * LSEQ + p] = h2;
}

// ---------- Kernel 2: k[d][p] = (h2 . Wf) * (exp(-t|delta|)+0.05) ---------
#define DCHUNK 96
__global__ __launch_bounds__(256)
void filter_kernel(const float* __restrict__ hws, const float* __restrict__ Wf,
                   float* __restrict__ kws)
{
    __shared__ float hsh[FO][257];
    const int tid = threadIdx.x;
    const int p  = blockIdx.x * 256 + tid;
    const int d0 = blockIdx.y * DCHUNK;
#pragma unroll 1
    for (int j = 0; j < FO; ++j) hsh[j][tid] = hws[j * LSEQ + p];
    __syncthreads();
    const float tt = (float)p / (float)(LSEQ - 1);
    const float min_decay = -3.0701134573253937f;
    const float max_decay = -15.350567286626971f;
#pragma unroll 1
    for (int c = 0; c < DCHUNK / 32; ++c) {
        const int dc = d0 + c * 32;
#define DEFA(I) float a##I = 0.f;
        REP32(DEFA)
#undef DEFA
#pragma unroll 4
        for (int j = 0; j < FO; ++j) {
            float hj = hsh[j][tid];
            const float* Wj = Wf + j * DIMC + dc;
#define FMA_(I) a##I = fmaf(hj, Wj[I], a##I);
            REP32(FMA_)
#undef FMA_
        }
#define ST_(I) { int d = dc + I; \
    float delta = min_decay + (max_decay - min_decay) * ((float)d / (float)(DIMC - 1)); \
    float dec = __expf(-tt * fabsf(delta)); \
    kws[(size_t)d * LSEQ + p] = a##I * (dec + 0.05f); }
        REP32(ST_)
#undef ST_
    }
}

// =================== MODE0: F=8192 overlap-add path =======================
// kfft8: per channel, pack the two REAL 4096 k-chunks as one complex FFT.
// K0(n)=(Z+conjZp)/2N, K1(n)=-i(Z-conjZp)/2N; digit map (8,8,8,8,2):
//   n = f0+8f1+64f2+512f3+4096g ; s = 1024f0+128f1+16f2+2f3+g
__global__ __launch_bounds__(1024)
void kfft8_kernel(const float* __restrict__ kf, const float* __restrict__ bias,
                  __half2* __restrict__ KF)
{
    __shared__ v2f L[8192];   // 64 KB -> 2 blocks/CU
    const int d = blockIdx.x, t = threadIdx.x;
    const float* kr = kf + (size_t)d * LSEQ;
    {
        float r0 = kr[t]; if (t == 0) r0 += bias[d];
        fwd8_first<1024>(L, t,
            (v2f){r0,            kr[4096 + t]},
            (v2f){kr[t + 1024],  kr[5120 + t]},
            (v2f){kr[t + 2048],  kr[6144 + t]},
            (v2f){kr[t + 3072],  kr[7168 + t]});
    }
    fwd8s<7, 1>(L, t);   // S=128
    fwd8s<4, 1>(L, t);   // S=16
    fwd8s<1, 1>(L, t);   // S=2
    // final r2 (S=1, trivial twiddle) in place
    __syncthreads();
    {
        int n0 = t << 3;
        v2f z0 = L[swz(n0)],     z1 = L[swz(n0 + 1)];
        v2f z2 = L[swz(n0 + 2)], z3 = L[swz(n0 + 3)];
        v2f z4 = L[swz(n0 + 4)], z5 = L[swz(n0 + 5)];
        v2f z6 = L[swz(n0 + 6)], z7 = L[swz(n0 + 7)];
        L[swz(n0)]     = z0 + z1; L[swz(n0 + 1)] = z0 - z1;
        L[swz(n0 + 2)] = z2 + z3; L[swz(n0 + 3)] = z2 - z3;
        L[swz(n0 + 4)] = z4 + z5; L[swz(n0 + 5)] = z4 - z5;
        L[swz(n0 + 6)] = z6 + z7; L[swz(n0 + 7)] = z6 - z7;
    }
    // Hermitian unpack + half2 store; 1/N folded here (the ONLY scaling)
    __syncthreads();
    const float hn = 0.5f / 8192.f;
    __half2* K0 = KF + (size_t)d * 16384;
    __half2* K1 = K0 + 8192;
#pragma unroll 1
    for (int i = 0; i < 8; ++i) {
        int s = (i << 10) + t;
        int f0 = s >> 10, f1 = (s >> 7) & 7, f2 = (s >> 4) & 7, f3 = (s >> 1) & 7, g = s & 1;
        int n  = f0 + (f1 << 3) + (f2 << 6) + (f3 << 9) + (g << 12);
        int np = (8192 - n) & 8191;
        int sp = ((np & 7) << 10) | (((np >> 3) & 7) << 7) | (((np >> 6) & 7) << 4)
               | (((np >> 9) & 7) << 1) | (np >> 12);
        v2f Zs = L[swz(s)];
        v2f Zp = L[swz(sp)];
        K0[s] = __floats2half2_rn((Zs.x + Zp.x) * hn, (Zs.y - Zp.y) * hn);
        K1[s] = __floats2half2_rn((Zs.y + Zp.y) * hn, (Zp.x - Zs.x) * hn);
    }
}

// conv8: per channel, two fwd+inv cycles (chunks A,B); C=K1*ZA in 16 regs;
// A-hi stashed into y-hi addresses, same-thread += after B.
__global__ __launch_bounds__(1024)
void conv8_kernel(const float* __restrict__ x, const __half2* __restrict__ KF,
                  float* __restrict__ out)
{
    __shared__ v2f L[8192];   // 64 KB -> 2 blocks/CU
    const int d = blockIdx.x, t = threadIdx.x;
    const float* x0 = x + (size_t)d * LSEQ;
    const float* x1 = x + (size_t)(DIMC + d) * LSEQ;
    float* o0 = out + (size_t)d * LSEQ;
    float* o1 = out + (size_t)(DIMC + d) * LSEQ;
    const __half2* K0 = KF + (size_t)d * 16384;
    const __half2* K1 = K0 + 8192;
    v2f C0, C1, C2, C3, C4, C5, C6, C7;   // persistent K1*ZA

    // ---------------- cycle A: chunk x[0:4096) ----------------
    fwd8_first<1024>(L, t,
        (v2f){x0[t],        x1[t]},
        (v2f){x0[t + 1024], x1[t + 1024]},
        (v2f){x0[t + 2048], x1[t + 2048]},
        (v2f){x0[t + 3072], x1[t + 3072]});
    fwd8s<7, 1>(L, t);
    fwd8s<4, 1>(L, t);
    fwd8s<1, 1>(L, t);
    __syncthreads();
    {   // fused: r2-fwd | A=K0*Z, C=K1*Z | r2-inv | write A'
        int n0 = t << 3;
        v2f z0 = L[swz(n0)],     z1 = L[swz(n0 + 1)];
        v2f z2 = L[swz(n0 + 2)], z3 = L[swz(n0 + 3)];
        v2f z4 = L[swz(n0 + 4)], z5 = L[swz(n0 + 5)];
        v2f z6 = L[swz(n0 + 6)], z7 = L[swz(n0 + 7)];
        v2f w0 = z0 + z1, w1 = z0 - z1, w2 = z2 + z3, w3 = z2 - z3;
        v2f w4 = z4 + z5, w5 = z4 - z5, w6 = z6 + z7, w7 = z6 - z7;
        v2f A0 = kmul(K0[n0],     w0), A1 = kmul(K0[n0 + 1], w1);
        v2f A2 = kmul(K0[n0 + 2], w2), A3 = kmul(K0[n0 + 3], w3);
        v2f A4 = kmul(K0[n0 + 4], w4), A5 = kmul(K0[n0 + 5], w5);
        v2f A6 = kmul(K0[n0 + 6], w6), A7 = kmul(K0[n0 + 7], w7);
        C0 = kmul(K1[n0],     w0); C1 = kmul(K1[n0 + 1], w1);
        C2 = kmul(K1[n0 + 2], w2); C3 = kmul(K1[n0 + 3], w3);
        C4 = kmul(K1[n0 + 4], w4); C5 = kmul(K1[n0 + 5], w5);
        C6 = kmul(K1[n0 + 6], w6); C7 = kmul(K1[n0 + 7], w7);
        L[swz(n0)]     = A0 + A1; L[swz(n0 + 1)] = A0 - A1;
        L[swz(n0 + 2)] = A2 + A3; L[swz(n0 + 3)] = A2 - A3;
        L[swz(n0 + 4)] = A4 + A5; L[swz(n0 + 5)] = A4 - A5;
        L[swz(n0 + 6)] = A6 + A7; L[swz(n0 + 7)] = A6 - A7;
    }
    inv8s<1, 1>(L, t);
    inv8s<4, 1>(L, t);
    inv8s<7, 1>(L, t);
    // final inv S=1024 (full): y-lo final, hi half = stash into y-hi slots
    __syncthreads();
    {
        float th = (float)t * (PI_F / 4096.0f);
        TWCHAIN7(th);
        v2f y0 = L[swz(t)];
        v2f y1 = cmulp(L[swz(t + 1024)], c1, s1);
        v2f y2 = cmulp(L[swz(t + 2048)], c2, s2);
        v2f y3 = cmulp(L[swz(t + 3072)], c3, s3);
        v2f y4 = cmulp(L[swz(t + 4096)], c4, s4);
        v2f y5 = cmulp(L[swz(t + 5120)], c5, s5);
        v2f y6 = cmulp(L[swz(t + 6144)], c6, s6);
        v2f y7 = cmulp(L[swz(t + 7168)], c7, s7);
        v2f E0 = y0 + y4, F0 = y0 - y4;
        v2f E1 = y2 + y6, F1 = pli(y2 - y6);
        v2f a0 = E0 + E1, a2 = E0 - E1;
        v2f a1 = F0 + F1, a3 = F0 - F1;
        v2f G0 = y1 + y5, H0 = y1 - y5;
        v2f G1 = y3 + y7, H1 = pli(y3 - y7);
        v2f w0 = G0 + G1, w2 = G0 - G1;
        v2f w1 = H0 + H1, w3 = H0 - H1;
        v2f b0 = w0;
        v2f b1 = cmulp(w1,  RSQ2, RSQ2);
        v2f b2 = pli(w2);
        v2f b3 = cmulp(w3, -RSQ2, RSQ2);
        v2f r0 = a0 + b0, r1 = a1 + b1, r2 = a2 + b2, r3 = a3 + b3;
        v2f r4 = a0 - b0, r5 = a1 - b1, r6 = a2 - b2, r7 = a3 - b3;
        o0[t]        = r0.x; o1[t]        = r0.y;
        o0[t + 1024] = r1.x; o1[t + 1024] = r1.y;
        o0[t + 2048] = r2.x; o1[t + 2048] = r2.y;
        o0[t + 3072] = r3.x; o1[t + 3072] = r3.y;
        o0[t + 4096] = r4.x; o1[t + 4096] = r4.y;   // stash A-hi
        o0[t + 5120] = r5.x; o1[t + 5120] = r5.y;
        o0[t + 6144] = r6.x; o1[t + 6144] = r6.y;
        o0[t + 7168] = r7.x; o1[t + 7168] = r7.y;
    }
    // ---------------- cycle B: chunk x[4096:8192) ----------------
    __syncthreads();   // WAR: final pass read L; fwd_first writes it
    fwd8_first<1024>(L, t,
        (v2f){x0[4096 + t],        x1[4096 + t]},
        (v2f){x0[5120 + t],        x1[5120 + t]},
        (v2f){x0[6144 + t],        x1[6144 + t]},
        (v2f){x0[7168 + t],        x1[7168 + t]});
    fwd8s<7, 1>(L, t);
    fwd8s<4, 1>(L, t);
    fwd8s<1, 1>(L, t);
    __syncthreads();
    {   // fused: r2-fwd | B=K0*Z + C | r2-inv | write B'
        int n0 = t << 3;
        v2f z0 = L[swz(n0)],     z1 = L[swz(n0 + 1)];
        v2f z2 = L[swz(n0 + 2)], z3 = L[swz(n0 + 3)];
        v2f z4 = L[swz(n0 + 4)], z5 = L[swz(n0 + 5)];
        v2f z6 = L[swz(n0 + 6)], z7 = L[swz(n0 + 7)];
        v2f w0 = z0 + z1, w1 = z0 - z1, w2 = z2 + z3, w3 = z2 - z3;
        v2f w4 = z4 + z5, w5 = z4 - z5, w6 = z6 + z7, w7 = z6 - z7;
        v2f B0 = kmul(K0[n0],     w0) + C0, B1 = kmul(K0[n0 + 1], w1) + C1;
        v2f B2 = kmul(K0[n0 + 2], w2) + C2, B3 = kmul(K0[n0 + 3], w3) + C3;
        v2f B4 = kmul(K0[n0 + 4], w4) + C4, B5 = kmul(K0[n0 + 5], w5) + C5;
        v2f B6 = kmul(K0[n0 + 6], w6) + C6, B7 = kmul(K0[n0 + 7], w7) + C7;
        L[swz(n0)]     = B0 + B1; L[swz(n0 + 1)] = B0 - B1;
        L[swz(n0 + 2)] = B2 + B3; L[swz(n0 + 3)] = B2 - B3;
        L[swz(n0 + 4)] = B4 + B5; L[swz(n0 + 5)] = B4 - B5;
        L[swz(n0 + 6)] = B6 + B7; L[swz(n0 + 7)] = B6 - B7;
    }
    inv8s<1, 1>(L, t);
    inv8s<4, 1>(L, t);
    inv8s<7, 1>(L, t);
    // final inv S=1024 truncated (lo half only): y-hi += invB-lo
    __syncthreads();
    {
        float th = (float)t * (PI_F / 4096.0f);
        TWCHAIN7(th);
        v2f y0 = L[swz(t)];
        v2f y1 = cmulp(L[swz(t + 1024)], c1, s1);
        v2f y2 = cmulp(L[swz(t + 2048)], c2, s2);
        v2f y3 = cmulp(L[swz(t + 3072)], c3, s3);
        v2f y4 = cmulp(L[swz(t + 4096)], c4, s4);
        v2f y5 = cmulp(L[swz(t + 5120)], c5, s5);
        v2f y6 = cmulp(L[swz(t + 6144)], c6, s6);
        v2f y7 = cmulp(L[swz(t + 7168)], c7, s7);
        v2f E0 = y0 + y4;
        v2f E1 = y2 + y6, F0 = y0 - y4, F1 = pli(y2 - y6);
        v2f a0 = E0 + E1, a2 = E0 - E1;
        v2f a1 = F0 + F1, a3 = F0 - F1;
        v2f G0 = y1 + y5, H0 = y1 - y5;
        v2f G1 = y3 + y7, H1 = pli(y3 - y7);
        v2f w0 = G0 + G1, w2 = G0 - G1;
        v2f w1 = H0 + H1, w3 = H0 - H1;
        v2f b0 = w0;
        v2f b1 = cmulp(w1,  RSQ2, RSQ2);
        v2f b2 = pli(w2);
        v2f b3 = cmulp(w3, -RSQ2, RSQ2);
        v2f r0 = a0 + b0, r1 = a1 + b1, r2 = a2 + b2, r3 = a3 + b3;
        o0[4096 + t] += r0.x;  o1[4096 + t] += r0.y;   // same-thread RMW
        o0[5120 + t] += r1.x;  o1[5120 + t] += r1.y;
        o0[6144 + t] += r2.x;  o1[6144 + t] += r2.y;
        o0[7168 + t] += r3.x;  o1[7168 + t] += r3.y;
    }
}

// =================== MODE1: validated F=16384 fallback ====================
__global__ __launch_bounds__(1024)
void kfft_kernel1(const float* __restrict__ kf, const float* __restrict__ bias,
                  float* __restrict__ outbase)
{
    __shared__ v2f L[NF];
    const int g = blockIdx.x, t = threadIdx.x;
    const int da = 2 * g, db = 2 * g + 1;
    const float* ka = kf + (size_t)da * LSEQ;
    const float* kb = kf + (size_t)db * LSEQ;
#pragma unroll 1
    for (int m = 0; m < 2; ++m) {
        int q = t + (m << 10);
        float vr = ka[q], vi = kb[q];
        if (q == 0) { vr += bias[da]; vi += bias[db]; }
        fwd8_first<2048>(L, q, (v2f){vr, vi},
                   (v2f){ka[q + 2048], kb[q + 2048]},
                   (v2f){ka[q + 4096], kb[q + 4096]},
                   (v2f){ka[q + 6144], kb[q + 6144]});
    }
    fwd8s<8, 2>(L, t);
    fwd8s<5, 2>(L, t);
    fwd8s<2, 2>(L, t);
    __syncthreads();
#pragma unroll 1
    for (int ch = 0; ch < 2; ++ch) {
        int n0 = (t << 4) + (ch << 3);
        v2f z0 = L[swz(n0)],     z1 = L[swz(n0 + 1)];
        v2f z2 = L[swz(n0 + 2)], z3 = L[swz(n0 + 3)];
        v2f z4 = L[swz(n0 + 4)], z5 = L[swz(n0 + 5)];
        v2f z6 = L[swz(n0 + 6)], z7 = L[swz(n0 + 7)];
        bf4f0(z0, z1, z2, z3); bf4f0(z4, z5, z6, z7);
        L[swz(n0)]     = z0; L[swz(n0 + 1)] = z1;
        L[swz(n0 + 2)] = z2; L[swz(n0 + 3)] = z3;
        L[swz(n0 + 4)] = z4; L[swz(n0 + 5)] = z5;
        L[swz(n0 + 6)] = z6; L[swz(n0 + 7)] = z7;
    }
    __syncthreads();
    const float hn = 0.5f / 16384.f;
#pragma unroll 1
    for (int i = 0; i < 16; ++i) {
        int s = (i << 10) + t;
        int D0 = s >> 11, D1 = (s >> 8) & 7, D2 = (s >> 5) & 7, D3 = (s >> 2) & 7, E = s & 3;
        int n  = D0 + (D1 << 3) + (D2 << 6) + (D3 << 9) + (E << 12);
        int np = (16384 - n) & 16383;
        int sp = ((np & 7) << 11) | (((np >> 3) & 7) << 8) | (((np >> 6) & 7) << 5)
               | (((np >> 9) & 7) << 2) | ((np >> 12) & 3);
        v2f Zs = L[swz(s)];
        v2f Zp = L[swz(sp)];
        float kar = (Zs.x + Zp.x) * hn, kai = (Zs.y - Zp.y) * hn;
        float kbr = (Zs.y + Zp.y) * hn, kbi = (Zp.x - Zs.x) * hn;
        __half2* Ha = (s < 8192)
            ? (__half2*)(outbase + (size_t)da * LSEQ) + s
            : (__half2*)(outbase + (size_t)(DIMC + da) * LSEQ) + (s - 8192);
        __half2* Hb = (s < 8192)
            ? (__half2*)(outbase + (size_t)db * LSEQ) + s
            : (__half2*)(outbase + (size_t)(DIMC + db) * LSEQ) + (s - 8192);
        *Ha = __floats2half2_rn(kar, kai);
        *Hb = __floats2half2_rn(kbr, kbi);
    }
}

__global__ __launch_bounds__(1024)
void conv_kernel1(const float* __restrict__ x, float* __restrict__ out)
{
    __shared__ v2f L[NF];
    const int d = blockIdx.x, t = threadIdx.x;
    const float* x0 = x + (size_t)d * LSEQ;
    const float* x1 = x + (size_t)(DIMC + d) * LSEQ;
    float* o0 = out + (size_t)d * LSEQ;
    float* o1 = out + (size_t)(DIMC + d) * LSEQ;
#pragma unroll 1
    for (int m = 0; m < 2; ++m) {
        int q = t + (m << 10);
        fwd8_first<2048>(L, q, (v2f){x0[q], x1[q]},
                   (v2f){x0[q + 2048], x1[q + 2048]},
                   (v2f){x0[q + 4096], x1[q + 4096]},
                   (v2f){x0[q + 6144], x1[q + 6144]});
    }
    fwd8s<8, 2>(L, t);
    fwd8s<5, 2>(L, t);
    fwd8s<2, 2>(L, t);
    __syncthreads();
#pragma unroll 1
    for (int ch = 0; ch < 2; ++ch) {
        int n0 = (t << 4) + (ch << 3);
        v2f z0 = L[swz(n0)],     z1 = L[swz(n0 + 1)];
        v2f z2 = L[swz(n0 + 2)], z3 = L[swz(n0 + 3)];
        v2f z4 = L[swz(n0 + 4)], z5 = L[swz(n0 + 5)];
        v2f z6 = L[swz(n0 + 6)], z7 = L[swz(n0 + 7)];
        bf4f0(z0, z1, z2, z3); bf4f0(z4, z5, z6, z7);
        const __half2* H = (n0 < 8192)
            ? (const __half2*)(out + (size_t)d * LSEQ) + n0
            : (const __half2*)(out + (size_t)(DIMC + d) * LSEQ) + (n0 - 8192);
        z0 = kmul(H[0], z0); z1 = kmul(H[1], z1);
        z2 = kmul(H[2], z2); z3 = kmul(H[3], z3);
        z4 = kmul(H[4], z4); z5 = kmul(H[5], z5);
        z6 = kmul(H[6], z6); z7 = kmul(H[7], z7);
        bf4i0(z0, z1, z2, z3); bf4i0(z4, z5, z6, z7);
        L[swz(n0)]     = z0; L[swz(n0 + 1)] = z1;
        L[swz(n0 + 2)] = z2; L[swz(n0 + 3)] = z3;
        L[swz(n0 + 4)] = z4; L[swz(n0 + 5)] = z5;
        L[swz(n0 + 6)] = z6; L[swz(n0 + 7)] = z7;
    }
    inv8s<2, 2>(L, t);
    inv8s<5, 2>(L, t);
    inv8s<8, 2>(L, t);
    __syncthreads();
#pragma unroll 1
    for (int m = 0; m < 2; ++m) {
        int q = t + (m << 10);
        float th = (float)q * (PI_F / 8192.0f);
        TWCHAIN7(th);
        v2f y0 = L[swz(q)];
        v2f y1 = cmulp(L[swz(q + 2048)],  c1, s1);
        v2f y2 = cmulp(L[swz(q + 4096)],  c2, s2);
        v2f y3 = cmulp(L[swz(q + 6144)],  c3, s3);
        v2f y4 = cmulp(L[swz(q + 8192)],  c4, s4);
        v2f y5 = cmulp(L[swz(q + 10240)], c5, s5);
        v2f y6 = cmulp(L[swz(q + 12288)], c6, s6);
        v2f y7 = cmulp(L[swz(q + 14336)], c7, s7);
        v2f E0 = y0 + y4, F0 = y0 - y4;
        v2f E1 = y2 + y6, F1 = pli(y2 - y6);
        v2f a0 = E0 + E1, a2 = E0 - E1;
        v2f a1 = F0 + F1, a3 = F0 - F1;
        v2f G0 = y1 + y5, H0 = y1 - y5;
        v2f G1 = y3 + y7, H1 = pli(y3 - y7);
        v2f w0 = G0 + G1, w2 = G0 - G1;
        v2f w1 = H0 + H1, w3 = H0 - H1;
        v2f b0 = w0;
        v2f b1 = cmulp(w1,  RSQ2, RSQ2);
        v2f b2 = pli(w2);
        v2f b3 = cmulp(w3, -RSQ2, RSQ2);
        v2f r0 = a0 + b0, r1 = a1 + b1, r2 = a2 + b2, r3 = a3 + b3;
        o0[q]        = r0.x;  o1[q]        = r0.y;
        o0[q + 2048] = r1.x;  o1[q + 2048] = r1.y;
        o0[q + 4096] = r2.x;  o1[q + 4096] = r2.y;
        o0[q + 6144] = r3.x;  o1[q + 6144] = r3.y;
    }
}

extern "C" void kernel_launch(void* const* d_in, const int* in_sizes, int n_in,
                              void* d_out, int out_size, void* d_ws, size_t ws_size,
                              hipStream_t stream)
{
    (void)in_sizes; (void)n_in; (void)out_size;
    const float* x    = (const float*)d_in[0];
    const float* W0   = (const float*)d_in[1];
    const float* b0   = (const float*)d_in[2];
    const float* W1   = (const float*)d_in[3];
    const float* b1   = (const float*)d_in[4];
    const float* W2   = (const float*)d_in[5];
    const float* b2   = (const float*)d_in[6];
    const float* Wf   = (const float*)d_in[7];
    const float* freq = (const float*)d_in[8];
    const float* bias = (const float*)d_in[9];
    float* out = (float*)d_out;

    float* hws = out;                            // h2 staged in out rows 0..63
    float* kws = out + (size_t)DIMC * LSEQ;      // k staged in out rows 768..1535

    hipLaunchKernelGGL(hidden_kernel, dim3(LSEQ / 4), dim3(256), 0, stream,
                       W0, b0, W1, b1, W2, b2, freq, hws);
    hipLaunchKernelGGL(filter_kernel, dim3(LSEQ / 256, DIMC / DCHUNK), dim3(256), 0, stream,
                       hws, Wf, kws);

    const size_t kbytes = (size_t)DIMC * 2 * 8192 * sizeof(__half2);   // 50 MB
    if (ws_size >= kbytes) {
        __half2* KF = (__half2*)d_ws;
        hipLaunchKernelGGL(kfft8_kernel, dim3(DIMC), dim3(1024), 0, stream,
                           kws, bias, KF);
        hipLaunchKernelGGL(conv8_kernel, dim3(DIMC), dim3(1024), 0, stream,
                           x, KF, out);
    } else {
        hipLaunchKernelGGL(kfft_kernel1, dim3(DIMC / 2), dim3(1024), 0, stream,
                           kws, bias, out);
        hipLaunchKernelGGL(conv_kernel1, dim3(DIMC), dim3(1024), 0, stream,
                           x, out);
    }
}

// Round 19
// 280.897 us; speedup vs baseline: 1.1418x; 1.1418x over previous
//
#include <hip/hip_runtime.h>
#include <hip/hip_fp16.h>

// HyenaFilter = implicit-filter MLP (tiny) + FFT convolution.
// fftconv == causal linear conv; bias folded into k[0].
// R19: overlap-add (F=8192, 64KB LDS -> 2 blocks/CU) with the cross-cycle
//   spectrum C = K1*ZA stashed to d_ws as half2 instead of registers.
//   R18 held C in 16 regs across cycle-B's barriers -> spilled (531MB).
//   Rule learned (R5/R14/R18): NO register state across FFT stages at the
//   64-VGPR cap. kfft8 (verified R18) + R17-validated MODE1 fallback.

#define DIMC  768
#define BANDS 16
#define FO    64
#define LSEQ  8192
#define NF    16384
#define PI_F  3.14159265358979323846f
#define RSQ2  0.70710678118654752f

typedef float v2f __attribute__((ext_vector_type(2)));

#define REP32(M) M(0) M(1) M(2) M(3) M(4) M(5) M(6) M(7) M(8) M(9) M(10) M(11) \
    M(12) M(13) M(14) M(15) M(16) M(17) M(18) M(19) M(20) M(21) M(22) M(23) \
    M(24) M(25) M(26) M(27) M(28) M(29) M(30) M(31)

__device__ __forceinline__ int swz(int i) { return i ^ ((i >> 4) & 15); }

__device__ __forceinline__ v2f mni(v2f v) { v2f t = v.yx; t.y = -t.y; return t; } // -i*v
__device__ __forceinline__ v2f pli(v2f v) { v2f t = v.yx; t.x = -t.x; return t; } // +i*v
__device__ __forceinline__ v2f cmulm(v2f x, float c, float s) {   // x*(c - i s)
    v2f t = x.yx; t.y = -t.y;
    return x * c + t * s;
}
__device__ __forceinline__ v2f cmulp(v2f x, float c, float s) {   // x*(c + i s)
    v2f t = x.yx; t.x = -t.x;
    return x * c + t * s;
}
__device__ __forceinline__ v2f kmul(__half2 kh, v2f z) {          // z * k
    float2 kk = __half22float2(kh);
    v2f k = {kk.x, kk.y};
    return k * z.x + pli(k) * z.y;
}
__device__ __forceinline__ __half2 toh2(v2f v) { return __floats2half2_rn(v.x, v.y); }
__device__ __forceinline__ v2f frh2(__half2 h) { float2 f = __half22float2(h); return (v2f){f.x, f.y}; }

#define TWCHAIN7(TH) \
    float c1=__cosf(TH), s1=__sinf(TH); \
    float c2=c1*c1-s1*s1, s2=2.f*c1*s1; \
    float c3=c1*c2-s1*s2, s3=s1*c2+c1*s2; \
    float c4=c2*c2-s2*s2, s4=2.f*c2*s2; \
    float c5=c2*c3-s2*s3, s5=s2*c3+c2*s3; \
    float c6=c3*c3-s3*s3, s6=2.f*c3*s3; \
    float c7=c3*c4-s3*s4, s7=s3*c4+c3*s4

// ---- radix-8 fwd DIF stage; MIT butterflies/thread -----------------------
template<int SH, int MIT>
__device__ __forceinline__ void fwd8s(v2f* L, int t)
{
    __syncthreads();
    const int S = 1 << SH;
#pragma unroll 1
    for (int m = 0; m < MIT; ++m) {
        int b = t + (m << 10);
        int q = b & (S - 1);
        int p = ((b >> SH) << (SH + 3)) + q;
        v2f u0 = L[swz(p)];
        v2f u1 = L[swz(p + S)];
        v2f u2 = L[swz(p + 2 * S)];
        v2f u3 = L[swz(p + 3 * S)];
        v2f u4 = L[swz(p + 4 * S)];
        v2f u5 = L[swz(p + 5 * S)];
        v2f u6 = L[swz(p + 6 * S)];
        v2f u7 = L[swz(p + 7 * S)];
        v2f a0 = u0 + u4, b0 = u0 - u4;
        v2f a1 = u1 + u5, b1 = u1 - u5;
        v2f a2 = u2 + u6, b2 = u2 - u6;
        v2f a3 = u3 + u7, b3 = u3 - u7;
        v2f e0 = a0 + a2, e1 = a0 - a2;
        v2f f0 = a1 + a3, f1 = a1 - a3;
        v2f y0 = e0 + f0, y4 = e0 - f0;
        v2f nf1 = mni(f1);
        v2f y2 = e1 + nf1, y6 = e1 - nf1;
        v2f v1 = cmulm(b1,  RSQ2, RSQ2);
        v2f v2 = mni(b2);
        v2f v3 = cmulm(b3, -RSQ2, RSQ2);
        v2f g0 = b0 + v2, g1 = b0 - v2;
        v2f h0 = v1 + v3, h1 = v1 - v3;
        v2f y1 = g0 + h0, y5 = g0 - h0;
        v2f nh1 = mni(h1);
        v2f y3 = g1 + nh1, y7 = g1 - nh1;
        float th = (float)q * (PI_F / (4.0f * (float)S));
        TWCHAIN7(th);
        L[swz(p)]         = y0;
        L[swz(p + S)]     = cmulm(y1, c1, s1);
        L[swz(p + 2 * S)] = cmulm(y2, c2, s2);
        L[swz(p + 3 * S)] = cmulm(y3, c3, s3);
        L[swz(p + 4 * S)] = cmulm(y4, c4, s4);
        L[swz(p + 5 * S)] = cmulm(y5, c5, s5);
        L[swz(p + 6 * S)] = cmulm(y6, c6, s6);
        L[swz(p + 7 * S)] = cmulm(y7, c7, s7);
    }
}

// first fwd stage, zero-padded input (u4..u7 = 0); NS = N/8
template<int NS>
__device__ __forceinline__ void fwd8_first(v2f* L, int q,
                                           v2f u0, v2f u1, v2f u2, v2f u3)
{
    v2f e0 = u0 + u2, e1 = u0 - u2;
    v2f f0 = u1 + u3, f1 = u1 - u3;
    v2f y0 = e0 + f0, y4 = e0 - f0;
    v2f nf1 = mni(f1);
    v2f y2 = e1 + nf1, y6 = e1 - nf1;
    v2f v1 = cmulm(u1,  RSQ2, RSQ2);
    v2f v2 = mni(u2);
    v2f v3 = cmulm(u3, -RSQ2, RSQ2);
    v2f g0 = u0 + v2, g1 = u0 - v2;
    v2f h0 = v1 + v3, h1 = v1 - v3;
    v2f y1 = g0 + h0, y5 = g0 - h0;
    v2f nh1 = mni(h1);
    v2f y3 = g1 + nh1, y7 = g1 - nh1;
    float th = (float)q * (PI_F / (4.0f * (float)NS));
    TWCHAIN7(th);
    L[swz(q)]          = y0;
    L[swz(q + NS)]     = cmulm(y1, c1, s1);
    L[swz(q + 2 * NS)] = cmulm(y2, c2, s2);
    L[swz(q + 3 * NS)] = cmulm(y3, c3, s3);
    L[swz(q + 4 * NS)] = cmulm(y4, c4, s4);
    L[swz(q + 5 * NS)] = cmulm(y5, c5, s5);
    L[swz(q + 6 * NS)] = cmulm(y6, c6, s6);
    L[swz(q + 7 * NS)] = cmulm(y7, c7, s7);
}

// ---- radix-8 inv DIT stage ------------------------------------------------
template<int SH, int MIT>
__device__ __forceinline__ void inv8s(v2f* L, int t)
{
    __syncthreads();
    const int S = 1 << SH;
#pragma unroll 1
    for (int m = 0; m < MIT; ++m) {
        int b = t + (m << 10);
        int q = b & (S - 1);
        int p = ((b >> SH) << (SH + 3)) + q;
        float th = (float)q * (PI_F / (4.0f * (float)S));
        TWCHAIN7(th);
        v2f y0 = L[swz(p)];
        v2f y1 = cmulp(L[swz(p + S)],     c1, s1);
        v2f y2 = cmulp(L[swz(p + 2*S)],   c2, s2);
        v2f y3 = cmulp(L[swz(p + 3*S)],   c3, s3);
        v2f y4 = cmulp(L[swz(p + 4*S)],   c4, s4);
        v2f y5 = cmulp(L[swz(p + 5*S)],   c5, s5);
        v2f y6 = cmulp(L[swz(p + 6*S)],   c6, s6);
        v2f y7 = cmulp(L[swz(p + 7*S)],   c7, s7);
        v2f E0 = y0 + y4, F0 = y0 - y4;
        v2f E1 = y2 + y6, F1 = pli(y2 - y6);
        v2f a0 = E0 + E1, a2 = E0 - E1;
        v2f a1 = F0 + F1, a3 = F0 - F1;
        v2f G0 = y1 + y5, H0 = y1 - y5;
        v2f G1 = y3 + y7, H1 = pli(y3 - y7);
        v2f w0 = G0 + G1, w2 = G0 - G1;
        v2f w1 = H0 + H1, w3 = H0 - H1;
        v2f b0 = w0;
        v2f b1 = cmulp(w1,  RSQ2, RSQ2);
        v2f b2 = pli(w2);
        v2f b3 = cmulp(w3, -RSQ2, RSQ2);
        L[swz(p)]         = a0 + b0;
        L[swz(p + S)]     = a1 + b1;
        L[swz(p + 2 * S)] = a2 + b2;
        L[swz(p + 3 * S)] = a3 + b3;
        L[swz(p + 4 * S)] = a0 - b0;
        L[swz(p + 5 * S)] = a1 - b1;
        L[swz(p + 6 * S)] = a2 - b2;
        L[swz(p + 7 * S)] = a3 - b3;
    }
}

// trivial-twiddle radix-4 (S=1) fwd / inv (packed) — MODE1 path
__device__ __forceinline__ void bf4f0(v2f& a, v2f& b, v2f& c, v2f& d)
{
    v2f A = a + c, B = a - c, C = b + d, D = mni(b - d);
    a = A + C; b = B + D; c = A - C; d = B - D;
}
__device__ __forceinline__ void bf4i0(v2f& a, v2f& b, v2f& c, v2f& d)
{
    v2f e0 = a + c, e1 = a - c, f0 = b + d, f1 = pli(b - d);
    a = e0 + f0; b = e1 + f1; c = e0 - f0; d = e1 - f1;
}

// ---------- Kernel 1: MLP hidden states h2[FO][LSEQ] ----------------------
__global__ void hidden_kernel(const float* __restrict__ W0, const float* __restrict__ b0,
                              const float* __restrict__ W1, const float* __restrict__ b1,
                              const float* __restrict__ W2, const float* __restrict__ b2,
                              const float* __restrict__ freq, float* __restrict__ hws)
{
    const int lane = threadIdx.x & 63;
    const int p = blockIdx.x * (blockDim.x >> 6) + (threadIdx.x >> 6);
    if (p >= LSEQ) return;
    const float tt = (float)p / (float)(LSEQ - 1);
    const float w  = 6.283185307179586f * (float)p / (float)LSEQ;

    float acc = b0[lane] + tt * W0[lane];
#pragma unroll
    for (int j = 0; j < BANDS; ++j) {
        float f = 1e-4f + (float)j * ((15.0f - 1e-4f) / 15.0f);
        float a = f * w;
        acc += __cosf(a)  * W0[(1 + j) * FO + lane];
        acc += -__sinf(a) * W0[(1 + BANDS + j) * FO + lane];
    }
    float h = __sinf(freq[lane] * acc);

    acc = b1[lane];
#pragma unroll
    for (int e = 0; e < FO; ++e) acc += __shfl(h, e) * W1[e * FO + lane];
    float h1 = __sinf(freq[lane] * acc);

    acc = b2[lane];
#pragma unroll
    for (int e = 0; e < FO; ++e) acc += __shfl(h1, e) * W2[e * FO + lane];
    float h2 = __sinf(freq[lane] * acc);

    hws[lane * LSEQ + p] = h2;
}

// ---------- Kernel 2: k[d][p] = (h2 . Wf) * (exp(-t|delta|)+0.05) ---------
#define DCHUNK 96
__global__ __launch_bounds__(256)
void filter_kernel(const float* __restrict__ hws, const float* __restrict__ Wf,
                   float* __restrict__ kws)
{
    __shared__ float hsh[FO][257];
    const int tid = threadIdx.x;
    const int p  = blockIdx.x * 256 + tid;
    const int d0 = blockIdx.y * DCHUNK;
#pragma unroll 1
    for (int j = 0; j < FO; ++j) hsh[j][tid] = hws[j * LSEQ + p];
    __syncthreads();
    const float tt = (float)p / (float)(LSEQ - 1);
    const float min_decay = -3.0701134573253937f;
    const float max_decay = -15.350567286626971f;
#pragma unroll 1
    for (int c = 0; c < DCHUNK / 32; ++c) {
        const int dc = d0 + c * 32;
#define DEFA(I) float a##I = 0.f;
        REP32(DEFA)
#undef DEFA
#pragma unroll 4
        for (int j = 0; j < FO; ++j) {
            float hj = hsh[j][tid];
            const float* Wj = Wf + j * DIMC + dc;
#define FMA_(I) a##I = fmaf(hj, Wj[I], a##I);
            REP32(FMA_)
#undef FMA_
        }
#define ST_(I) { int d = dc + I; \
    float delta = min_decay + (max_decay - min_decay) * ((float)d / (float)(DIMC - 1)); \
    float dec = __expf(-tt * fabsf(delta)); \
    kws[(size_t)d * LSEQ + p] = a##I * (dec + 0.05f); }
        REP32(ST_)
#undef ST_
    }
}

// =================== MODE0: F=8192 overlap-add path =======================
// kfft8 (verified R18): pack the two REAL 4096 k-chunks as one complex FFT.
__global__ __launch_bounds__(1024)
void kfft8_kernel(const float* __restrict__ kf, const float* __restrict__ bias,
                  __half2* __restrict__ KF)
{
    __shared__ v2f L[8192];   // 64 KB -> 2 blocks/CU
    const int d = blockIdx.x, t = threadIdx.x;
    const float* kr = kf + (size_t)d * LSEQ;
    {
        float r0 = kr[t]; if (t == 0) r0 += bias[d];
        fwd8_first<1024>(L, t,
            (v2f){r0,            kr[4096 + t]},
            (v2f){kr[t + 1024],  kr[5120 + t]},
            (v2f){kr[t + 2048],  kr[6144 + t]},
            (v2f){kr[t + 3072],  kr[7168 + t]});
    }
    fwd8s<7, 1>(L, t);   // S=128
    fwd8s<4, 1>(L, t);   // S=16
    fwd8s<1, 1>(L, t);   // S=2
    __syncthreads();
    {   // final r2 (S=1) in place
        int n0 = t << 3;
        v2f z0 = L[swz(n0)],     z1 = L[swz(n0 + 1)];
        v2f z2 = L[swz(n0 + 2)], z3 = L[swz(n0 + 3)];
        v2f z4 = L[swz(n0 + 4)], z5 = L[swz(n0 + 5)];
        v2f z6 = L[swz(n0 + 6)], z7 = L[swz(n0 + 7)];
        L[swz(n0)]     = z0 + z1; L[swz(n0 + 1)] = z0 - z1;
        L[swz(n0 + 2)] = z2 + z3; L[swz(n0 + 3)] = z2 - z3;
        L[swz(n0 + 4)] = z4 + z5; L[swz(n0 + 5)] = z4 - z5;
        L[swz(n0 + 6)] = z6 + z7; L[swz(n0 + 7)] = z6 - z7;
    }
    // Hermitian unpack (digit map (8,8,8,8,2)) + half2 store; 1/N folded
    __syncthreads();
    const float hn = 0.5f / 8192.f;
    __half2* K0 = KF + (size_t)d * 16384;
    __half2* K1 = K0 + 8192;
#pragma unroll 1
    for (int i = 0; i < 8; ++i) {
        int s = (i << 10) + t;
        int f0 = s >> 10, f1 = (s >> 7) & 7, f2 = (s >> 4) & 7, f3 = (s >> 1) & 7, g = s & 1;
        int n  = f0 + (f1 << 3) + (f2 << 6) + (f3 << 9) + (g << 12);
        int np = (8192 - n) & 8191;
        int sp = ((np & 7) << 10) | (((np >> 3) & 7) << 7) | (((np >> 6) & 7) << 4)
               | (((np >> 9) & 7) << 1) | (np >> 12);
        v2f Zs = L[swz(s)];
        v2f Zp = L[swz(sp)];
        K0[s] = __floats2half2_rn((Zs.x + Zp.x) * hn, (Zs.y - Zp.y) * hn);
        K1[s] = __floats2half2_rn((Zs.y + Zp.y) * hn, (Zp.x - Zs.x) * hn);
    }
}

// conv8: two fwd+inv cycles; C=K1*ZA stashed to GLOBAL half2 (no regs
// across barriers!); A-hi stashed into y-hi addresses, same-thread += later.
__global__ __launch_bounds__(1024)
void conv8_kernel(const float* __restrict__ x, const __half2* __restrict__ KF,
                  __half2* __restrict__ Cws, float* __restrict__ out)
{
    __shared__ v2f L[8192];   // 64 KB -> 2 blocks/CU
    const int d = blockIdx.x, t = threadIdx.x;
    const float* x0 = x + (size_t)d * LSEQ;
    const float* x1 = x + (size_t)(DIMC + d) * LSEQ;
    float* o0 = out + (size_t)d * LSEQ;
    float* o1 = out + (size_t)(DIMC + d) * LSEQ;
    const __half2* K0 = KF + (size_t)d * 16384;
    const __half2* K1 = K0 + 8192;
    __half2* Cp = Cws + (size_t)d * 8192;

    // ---------------- cycle A: chunk x[0:4096) ----------------
    fwd8_first<1024>(L, t,
        (v2f){x0[t],        x1[t]},
        (v2f){x0[t + 1024], x1[t + 1024]},
        (v2f){x0[t + 2048], x1[t + 2048]},
        (v2f){x0[t + 3072], x1[t + 3072]});
    fwd8s<7, 1>(L, t);
    fwd8s<4, 1>(L, t);
    fwd8s<1, 1>(L, t);
    __syncthreads();
    {   // fused: r2-fwd | A=K0*w, C=K1*w -> global | r2-inv(A)
        int n0 = t << 3;
        v2f z0 = L[swz(n0)],     z1 = L[swz(n0 + 1)];
        v2f z2 = L[swz(n0 + 2)], z3 = L[swz(n0 + 3)];
        v2f z4 = L[swz(n0 + 4)], z5 = L[swz(n0 + 5)];
        v2f z6 = L[swz(n0 + 6)], z7 = L[swz(n0 + 7)];
        {
            v2f w0 = z0 + z1, w1 = z0 - z1;
            Cp[n0]     = toh2(kmul(K1[n0],     w0));
            Cp[n0 + 1] = toh2(kmul(K1[n0 + 1], w1));
            v2f A0 = kmul(K0[n0], w0), A1 = kmul(K0[n0 + 1], w1);
            L[swz(n0)]     = A0 + A1; L[swz(n0 + 1)] = A0 - A1;
        }
        {
            v2f w2 = z2 + z3, w3 = z2 - z3;
            Cp[n0 + 2] = toh2(kmul(K1[n0 + 2], w2));
            Cp[n0 + 3] = toh2(kmul(K1[n0 + 3], w3));
            v2f A2 = kmul(K0[n0 + 2], w2), A3 = kmul(K0[n0 + 3], w3);
            L[swz(n0 + 2)] = A2 + A3; L[swz(n0 + 3)] = A2 - A3;
        }
        {
            v2f w4 = z4 + z5, w5 = z4 - z5;
            Cp[n0 + 4] = toh2(kmul(K1[n0 + 4], w4));
            Cp[n0 + 5] = toh2(kmul(K1[n0 + 5], w5));
            v2f A4 = kmul(K0[n0 + 4], w4), A5 = kmul(K0[n0 + 5], w5);
            L[swz(n0 + 4)] = A4 + A5; L[swz(n0 + 5)] = A4 - A5;
        }
        {
            v2f w6 = z6 + z7, w7 = z6 - z7;
            Cp[n0 + 6] = toh2(kmul(K1[n0 + 6], w6));
            Cp[n0 + 7] = toh2(kmul(K1[n0 + 7], w7));
            v2f A6 = kmul(K0[n0 + 6], w6), A7 = kmul(K0[n0 + 7], w7);
            L[swz(n0 + 6)] = A6 + A7; L[swz(n0 + 7)] = A6 - A7;
        }
    }
    inv8s<1, 1>(L, t);
    inv8s<4, 1>(L, t);
    inv8s<7, 1>(L, t);
    __syncthreads();
    {   // final inv S=1024 (full): y-lo final; A-hi stashed into y-hi slots
        float th = (float)t * (PI_F / 4096.0f);
        TWCHAIN7(th);
        v2f y0 = L[swz(t)];
        v2f y1 = cmulp(L[swz(t + 1024)], c1, s1);
        v2f y2 = cmulp(L[swz(t + 2048)], c2, s2);
        v2f y3 = cmulp(L[swz(t + 3072)], c3, s3);
        v2f y4 = cmulp(L[swz(t + 4096)], c4, s4);
        v2f y5 = cmulp(L[swz(t + 5120)], c5, s5);
        v2f y6 = cmulp(L[swz(t + 6144)], c6, s6);
        v2f y7 = cmulp(L[swz(t + 7168)], c7, s7);
        v2f E0 = y0 + y4, F0 = y0 - y4;
        v2f E1 = y2 + y6, F1 = pli(y2 - y6);
        v2f a0 = E0 + E1, a2 = E0 - E1;
        v2f a1 = F0 + F1, a3 = F0 - F1;
        v2f G0 = y1 + y5, H0 = y1 - y5;
        v2f G1 = y3 + y7, H1 = pli(y3 - y7);
        v2f w0 = G0 + G1, w2 = G0 - G1;
        v2f w1 = H0 + H1, w3 = H0 - H1;
        v2f b0 = w0;
        v2f b1 = cmulp(w1,  RSQ2, RSQ2);
        v2f b2 = pli(w2);
        v2f b3 = cmulp(w3, -RSQ2, RSQ2);
        v2f r0 = a0 + b0, r1 = a1 + b1, r2 = a2 + b2, r3 = a3 + b3;
        v2f r4 = a0 - b0, r5 = a1 - b1, r6 = a2 - b2, r7 = a3 - b3;
        o0[t]        = r0.x; o1[t]        = r0.y;
        o0[t + 1024] = r1.x; o1[t + 1024] = r1.y;
        o0[t + 2048] = r2.x; o1[t + 2048] = r2.y;
        o0[t + 3072] = r3.x; o1[t + 3072] = r3.y;
        o0[t + 4096] = r4.x; o1[t + 4096] = r4.y;   // stash A-hi
        o0[t + 5120] = r5.x; o1[t + 5120] = r5.y;
        o0[t + 6144] = r6.x; o1[t + 6144] = r6.y;
        o0[t + 7168] = r7.x; o1[t + 7168] = r7.y;
    }
    // ---------------- cycle B: chunk x[4096:8192) ----------------
    __syncthreads();   // WAR: final pass read L
    fwd8_first<1024>(L, t,
        (v2f){x0[4096 + t], x1[4096 + t]},
        (v2f){x0[5120 + t], x1[5120 + t]},
        (v2f){x0[6144 + t], x1[6144 + t]},
        (v2f){x0[7168 + t], x1[7168 + t]});
    fwd8s<7, 1>(L, t);
    fwd8s<4, 1>(L, t);
    fwd8s<1, 1>(L, t);
    __syncthreads();
    {   // fused: r2-fwd | B=K0*w + C(global) | r2-inv(B)
        int n0 = t << 3;
        v2f z0 = L[swz(n0)],     z1 = L[swz(n0 + 1)];
        v2f z2 = L[swz(n0 + 2)], z3 = L[swz(n0 + 3)];
        v2f z4 = L[swz(n0 + 4)], z5 = L[swz(n0 + 5)];
        v2f z6 = L[swz(n0 + 6)], z7 = L[swz(n0 + 7)];
        {
            v2f w0 = z0 + z1, w1 = z0 - z1;
            v2f B0 = kmul(K0[n0],     w0) + frh2(Cp[n0]);
            v2f B1 = kmul(K0[n0 + 1], w1) + frh2(Cp[n0 + 1]);
            L[swz(n0)]     = B0 + B1; L[swz(n0 + 1)] = B0 - B1;
        }
        {
            v2f w2 = z2 + z3, w3 = z2 - z3;
            v2f B2 = kmul(K0[n0 + 2], w2) + frh2(Cp[n0 + 2]);
            v2f B3 = kmul(K0[n0 + 3], w3) + frh2(Cp[n0 + 3]);
            L[swz(n0 + 2)] = B2 + B3; L[swz(n0 + 3)] = B2 - B3;
        }
        {
            v2f w4 = z4 + z5, w5 = z4 - z5;
            v2f B4 = kmul(K0[n0 + 4], w4) + frh2(Cp[n0 + 4]);
            v2f B5 = kmul(K0[n0 + 5], w5) + frh2(Cp[n0 + 5]);
            L[swz(n0 + 4)] = B4 + B5; L[swz(n0 + 5)] = B4 - B5;
        }
        {
            v2f w6 = z6 + z7, w7 = z6 - z7;
            v2f B6 = kmul(K0[n0 + 6], w6) + frh2(Cp[n0 + 6]);
            v2f B7 = kmul(K0[n0 + 7], w7) + frh2(Cp[n0 + 7]);
            L[swz(n0 + 6)] = B6 + B7; L[swz(n0 + 7)] = B6 - B7;
        }
    }
    inv8s<1, 1>(L, t);
    inv8s<4, 1>(L, t);
    inv8s<7, 1>(L, t);
    __syncthreads();
    {   // final inv S=1024 truncated: y-hi += invB-lo (same-thread RMW)
        float th = (float)t * (PI_F / 4096.0f);
        TWCHAIN7(th);
        v2f y0 = L[swz(t)];
        v2f y1 = cmulp(L[swz(t + 1024)], c1, s1);
        v2f y2 = cmulp(L[swz(t + 2048)], c2, s2);
        v2f y3 = cmulp(L[swz(t + 3072)], c3, s3);
        v2f y4 = cmulp(L[swz(t + 4096)], c4, s4);
        v2f y5 = cmulp(L[swz(t + 5120)], c5, s5);
        v2f y6 = cmulp(L[swz(t + 6144)], c6, s6);
        v2f y7 = cmulp(L[swz(t + 7168)], c7, s7);
        v2f E0 = y0 + y4, F0 = y0 - y4;
        v2f E1 = y2 + y6, F1 = pli(y2 - y6);
        v2f a0 = E0 + E1, a2 = E0 - E1;
        v2f a1 = F0 + F1, a3 = F0 - F1;
        v2f G0 = y1 + y5, H0 = y1 - y5;
        v2f G1 = y3 + y7, H1 = pli(y3 - y7);
        v2f w0 = G0 + G1, w2 = G0 - G1;
        v2f w1 = H0 + H1, w3 = H0 - H1;
        v2f b0 = w0;
        v2f b1 = cmulp(w1,  RSQ2, RSQ2);
        v2f b2 = pli(w2);
        v2f b3 = cmulp(w3, -RSQ2, RSQ2);
        v2f r0 = a0 + b0, r1 = a1 + b1, r2 = a2 + b2, r3 = a3 + b3;
        o0[4096 + t] += r0.x;  o1[4096 + t] += r0.y;
        o0[5120 + t] += r1.x;  o1[5120 + t] += r1.y;
        o0[6144 + t] += r2.x;  o1[6144 + t] += r2.y;
        o0[7168 + t] += r3.x;  o1[7168 + t] += r3.y;
    }
}

// =================== MODE1: validated F=16384 fallback ====================
__global__ __launch_bounds__(1024)
void kfft_kernel1(const float* __restrict__ kf, const float* __restrict__ bias,
                  float* __restrict__ outbase)
{
    __shared__ v2f L[NF];
    const int g = blockIdx.x, t = threadIdx.x;
    const int da = 2 * g, db = 2 * g + 1;
    const float* ka = kf + (size_t)da * LSEQ;
    const float* kb = kf + (size_t)db * LSEQ;
#pragma unroll 1
    for (int m = 0; m < 2; ++m) {
        int q = t + (m << 10);
        float vr = ka[q], vi = kb[q];
        if (q == 0) { vr += bias[da]; vi += bias[db]; }
        fwd8_first<2048>(L, q, (v2f){vr, vi},
                   (v2f){ka[q + 2048], kb[q + 2048]},
                   (v2f){ka[q + 4096], kb[q + 4096]},
                   (v2f){ka[q + 6144], kb[q + 6144]});
    }
    fwd8s<8, 2>(L, t);
    fwd8s<5, 2>(L, t);
    fwd8s<2, 2>(L, t);
    __syncthreads();
#pragma unroll 1
    for (int ch = 0; ch < 2; ++ch) {
        int n0 = (t << 4) + (ch << 3);
        v2f z0 = L[swz(n0)],     z1 = L[swz(n0 + 1)];
        v2f z2 = L[swz(n0 + 2)], z3 = L[swz(n0 + 3)];
        v2f z4 = L[swz(n0 + 4)], z5 = L[swz(n0 + 5)];
        v2f z6 = L[swz(n0 + 6)], z7 = L[swz(n0 + 7)];
        bf4f0(z0, z1, z2, z3); bf4f0(z4, z5, z6, z7);
        L[swz(n0)]     = z0; L[swz(n0 + 1)] = z1;
        L[swz(n0 + 2)] = z2; L[swz(n0 + 3)] = z3;
        L[swz(n0 + 4)] = z4; L[swz(n0 + 5)] = z5;
        L[swz(n0 + 6)] = z6; L[swz(n0 + 7)] = z7;
    }
    __syncthreads();
    const float hn = 0.5f / 16384.f;
#pragma unroll 1
    for (int i = 0; i < 16; ++i) {
        int s = (i << 10) + t;
        int D0 = s >> 11, D1 = (s >> 8) & 7, D2 = (s >> 5) & 7, D3 = (s >> 2) & 7, E = s & 3;
        int n  = D0 + (D1 << 3) + (D2 << 6) + (D3 << 9) + (E << 12);
        int np = (16384 - n) & 16383;
        int sp = ((np & 7) << 11) | (((np >> 3) & 7) << 8) | (((np >> 6) & 7) << 5)
               | (((np >> 9) & 7) << 2) | ((np >> 12) & 3);
        v2f Zs = L[swz(s)];
        v2f Zp = L[swz(sp)];
        float kar = (Zs.x + Zp.x) * hn, kai = (Zs.y - Zp.y) * hn;
        float kbr = (Zs.y + Zp.y) * hn, kbi = (Zp.x - Zs.x) * hn;
        __half2* Ha = (s < 8192)
            ? (__half2*)(outbase + (size_t)da * LSEQ) + s
            : (__half2*)(outbase + (size_t)(DIMC + da) * LSEQ) + (s - 8192);
        __half2* Hb = (s < 8192)
            ? (__half2*)(outbase + (size_t)db * LSEQ) + s
            : (__half2*)(outbase + (size_t)(DIMC + db) * LSEQ) + (s - 8192);
        *Ha = __floats2half2_rn(kar, kai);
        *Hb = __floats2half2_rn(kbr, kbi);
    }
}

__global__ __launch_bounds__(1024)
void conv_kernel1(const float* __restrict__ x, float* __restrict__ out)
{
    __shared__ v2f L[NF];
    const int d = blockIdx.x, t = threadIdx.x;
    const float* x0 = x + (size_t)d * LSEQ;
    const float* x1 = x + (size_t)(DIMC + d) * LSEQ;
    float* o0 = out + (size_t)d * LSEQ;
    float* o1 = out + (size_t)(DIMC + d) * LSEQ;
#pragma unroll 1
    for (int m = 0; m < 2; ++m) {
        int q = t + (m << 10);
        fwd8_first<2048>(L, q, (v2f){x0[q], x1[q]},
                   (v2f){x0[q + 2048], x1[q + 2048]},
                   (v2f){x0[q + 4096], x1[q + 4096]},
                   (v2f){x0[q + 6144], x1[q + 6144]});
    }
    fwd8s<8, 2>(L, t);
    fwd8s<5, 2>(L, t);
    fwd8s<2, 2>(L, t);
    __syncthreads();
#pragma unroll 1
    for (int ch = 0; ch < 2; ++ch) {
        int n0 = (t << 4) + (ch << 3);
        v2f z0 = L[swz(n0)],     z1 = L[swz(n0 + 1)];
        v2f z2 = L[swz(n0 + 2)], z3 = L[swz(n0 + 3)];
        v2f z4 = L[swz(n0 + 4)], z5 = L[swz(n0 + 5)];
        v2f z6 = L[swz(n0 + 6)], z7 = L[swz(n0 + 7)];
        bf4f0(z0, z1, z2, z3); bf4f0(z4, z5, z6, z7);
        const __half2* H = (n0 < 8192)
            ? (const __half2*)(out + (size_t)d * LSEQ) + n0
            : (const __half2*)(out + (size_t)(DIMC + d) * LSEQ) + (n0 - 8192);
        z0 = kmul(H[0], z0); z1 = kmul(H[1], z1);
        z2 = kmul(H[2], z2); z3 = kmul(H[3], z3);
        z4 = kmul(H[4], z4); z5 = kmul(H[5], z5);
        z6 = kmul(H[6], z6); z7 = kmul(H[7], z7);
        bf4i0(z0, z1, z2, z3); bf4i0(z4, z5, z6, z7);
        L[swz(n0)]     = z0; L[swz(n0 + 1)] = z1;
        L[swz(n0 + 2)] = z2; L[swz(n0 + 3)] = z3;
        L[swz(n0 + 4)] = z4; L[swz(n0 + 5)] = z5;
        L[swz(n0 + 6)] = z6; L[swz(n0 + 7)] = z7;
    }
    inv8s<2, 2>(L, t);
    inv8s<5, 2>(L, t);
    inv8s<8, 2>(L, t);
    __syncthreads();
#pragma unroll 1
    for (int m = 0; m < 2; ++m) {
        int q = t + (m << 10);
        float th = (float)q * (PI_F / 8192.0f);
        TWCHAIN7(th);
        v2f y0 = L[swz(q)];
        v2f y1 = cmulp(L[swz(q + 2048)],  c1, s1);
        v2f y2 = cmulp(L[swz(q + 4096)],  c2, s2);
        v2f y3 = cmulp(L[swz(q + 6144)],  c3, s3);
        v2f y4 = cmulp(L[swz(q + 8192)],  c4, s4);
        v2f y5 = cmulp(L[swz(q + 10240)], c5, s5);
        v2f y6 = cmulp(L[swz(q + 12288)], c6, s6);
        v2f y7 = cmulp(L[swz(q + 14336)], c7, s7);
        v2f E0 = y0 + y4, F0 = y0 - y4;
        v2f E1 = y2 + y6, F1 = pli(y2 - y6);
        v2f a0 = E0 + E1, a2 = E0 - E1;
        v2f a1 = F0 + F1, a3 = F0 - F1;
        v2f G0 = y1 + y5, H0 = y1 - y5;
        v2f G1 = y3 + y7, H1 = pli(y3 - y7);
        v2f w0 = G0 + G1, w2 = G0 - G1;
        v2f w1 = H0 + H1, w3 = H0 - H1;
        v2f b0 = w0;
        v2f b1 = cmulp(w1,  RSQ2, RSQ2);
        v2f b2 = pli(w2);
        v2f b3 = cmulp(w3, -RSQ2, RSQ2);
        v2f r0 = a0 + b0, r1 = a1 + b1, r2 = a2 + b2, r3 = a3 + b3;
        o0[q]        = r0.x;  o1[q]        = r0.y;
        o0[q + 2048] = r1.x;  o1[q + 2048] = r1.y;
        o0[q + 4096] = r2.x;  o1[q + 4096] = r2.y;
        o0[q + 6144] = r3.x;  o1[q + 6144] = r3.y;
    }
}

extern "C" void kernel_launch(void* const* d_in, const int* in_sizes, int n_in,
                              void* d_out, int out_size, void* d_ws, size_t ws_size,
                              hipStream_t stream)
{
    (void)in_sizes; (void)n_in; (void)out_size;
    const float* x    = (const float*)d_in[0];
    const float* W0   = (const float*)d_in[1];
    const float* b0   = (const float*)d_in[2];
    const float* W1   = (const float*)d_in[3];
    const float* b1   = (const float*)d_in[4];
    const float* W2   = (const float*)d_in[5];
    const float* b2   = (const float*)d_in[6];
    const float* Wf   = (const float*)d_in[7];
    const float* freq = (const float*)d_in[8];
    const float* bias = (const float*)d_in[9];
    float* out = (float*)d_out;

    float* hws = out;                            // h2 staged in out rows 0..63
    float* kws = out + (size_t)DIMC * LSEQ;      // k staged in out rows 768..1535

    hipLaunchKernelGGL(hidden_kernel, dim3(LSEQ / 4), dim3(256), 0, stream,
                       W0, b0, W1, b1, W2, b2, freq, hws);
    hipLaunchKernelGGL(filter_kernel, dim3(LSEQ / 256, DIMC / DCHUNK), dim3(256), 0, stream,
                       hws, Wf, kws);

    // ws layout: KF half2 [768*16384] (50.3 MB) then C half2 [768*8192] (25.2 MB)
    const size_t kf_elems = (size_t)DIMC * 16384;
    const size_t need = (kf_elems + (size_t)DIMC * 8192) * sizeof(__half2);
    if (ws_size >= need) {
        __half2* KF  = (__half2*)d_ws;
        __half2* Cws = KF + kf_elems;
        hipLaunchKernelGGL(kfft8_kernel, dim3(DIMC), dim3(1024), 0, stream,
                           kws, bias, KF);
        hipLaunchKernelGGL(conv8_kernel, dim3(DIMC), dim3(1024), 0, stream,
                           x, KF, Cws, out);
    } else {
        hipLaunchKernelGGL(kfft_kernel1, dim3(DIMC / 2), dim3(1024), 0, stream,
                           kws, bias, out);
        hipLaunchKernelGGL(conv_kernel1, dim3(DIMC), dim3(1024), 0, stream,
                           x, out);
    }
}

// Round 20
// 158.243 us; speedup vs baseline: 2.0269x; 1.7751x over previous
//
#include <hip/hip_runtime.h>
#include <hip/hip_fp16.h>

// HyenaFilter = implicit-filter MLP (tiny) + FFT convolution.
// fftconv (fft_size=16384 >= 2L) == causal linear conv; bias folded into k[0].
// R20 = R17 restored (best verified: 157.6us). R18/R19's F=8192 overlap-add
//   with 2 blocks/CU spilled both times (the 64-VGPR envelope admits ~8 live
//   complex points + one stage's temporaries; anything more spills — R5/R14/
//   R18/R19). Structure: radix-8 LDS-resident F=16384 FFT, packed-fp32 (v2f)
//   butterflies, half2 K-hat, paired-real kfft with Hermitian unpack,
//   j-outer/32-acc filter, wave-per-position hidden MLP.

#define DIMC  768
#define BANDS 16
#define FO    64
#define LSEQ  8192
#define NF    16384
#define PI_F  3.14159265358979323846f
#define RSQ2  0.70710678118654752f

typedef float v2f __attribute__((ext_vector_type(2)));

#define REP32(M) M(0) M(1) M(2) M(3) M(4) M(5) M(6) M(7) M(8) M(9) M(10) M(11) \
    M(12) M(13) M(14) M(15) M(16) M(17) M(18) M(19) M(20) M(21) M(22) M(23) \
    M(24) M(25) M(26) M(27) M(28) M(29) M(30) M(31)

__device__ __forceinline__ int swz(int i) { return i ^ ((i >> 4) & 15); }

__device__ __forceinline__ v2f mni(v2f v) { v2f t = v.yx; t.y = -t.y; return t; } // -i*v
__device__ __forceinline__ v2f pli(v2f v) { v2f t = v.yx; t.x = -t.x; return t; } // +i*v
__device__ __forceinline__ v2f cmulm(v2f x, float c, float s) {   // x*(c - i s)
    v2f t = x.yx; t.y = -t.y;
    return x * c + t * s;
}
__device__ __forceinline__ v2f cmulp(v2f x, float c, float s) {   // x*(c + i s)
    v2f t = x.yx; t.x = -t.x;
    return x * c + t * s;
}

#define TWCHAIN7(TH) \
    float c1=__cosf(TH), s1=__sinf(TH); \
    float c2=c1*c1-s1*s1, s2=2.f*c1*s1; \
    float c3=c1*c2-s1*s2, s3=s1*c2+c1*s2; \
    float c4=c2*c2-s2*s2, s4=2.f*c2*s2; \
    float c5=c2*c3-s2*s3, s5=s2*c3+c2*s3; \
    float c6=c3*c3-s3*s3, s6=2.f*c3*s3; \
    float c7=c3*c4-s3*s4, s7=s3*c4+c3*s4

// ---- full forward radix-8 DIF stage (packed) ------------------------------
template<int SH>
__device__ __forceinline__ void fwd8_stage(v2f* L, int t)
{
    __syncthreads();
    const int S = 1 << SH;
#pragma unroll 1
    for (int m = 0; m < 2; ++m) {
        int b = t + (m << 10);
        int q = b & (S - 1);
        int p = ((b >> SH) << (SH + 3)) + q;
        v2f u0 = L[swz(p)];
        v2f u1 = L[swz(p + S)];
        v2f u2 = L[swz(p + 2 * S)];
        v2f u3 = L[swz(p + 3 * S)];
        v2f u4 = L[swz(p + 4 * S)];
        v2f u5 = L[swz(p + 5 * S)];
        v2f u6 = L[swz(p + 6 * S)];
        v2f u7 = L[swz(p + 7 * S)];
        v2f a0 = u0 + u4, b0 = u0 - u4;
        v2f a1 = u1 + u5, b1 = u1 - u5;
        v2f a2 = u2 + u6, b2 = u2 - u6;
        v2f a3 = u3 + u7, b3 = u3 - u7;
        v2f e0 = a0 + a2, e1 = a0 - a2;
        v2f f0 = a1 + a3, f1 = a1 - a3;
        v2f y0 = e0 + f0, y4 = e0 - f0;
        v2f nf1 = mni(f1);
        v2f y2 = e1 + nf1, y6 = e1 - nf1;
        v2f v1 = cmulm(b1,  RSQ2, RSQ2);
        v2f v2 = mni(b2);
        v2f v3 = cmulm(b3, -RSQ2, RSQ2);
        v2f g0 = b0 + v2, g1 = b0 - v2;
        v2f h0 = v1 + v3, h1 = v1 - v3;
        v2f y1 = g0 + h0, y5 = g0 - h0;
        v2f nh1 = mni(h1);
        v2f y3 = g1 + nh1, y7 = g1 - nh1;
        float th = (float)q * (PI_F / (4.0f * (float)S));
        TWCHAIN7(th);
        L[swz(p)]         = y0;
        L[swz(p + S)]     = cmulm(y1, c1, s1);
        L[swz(p + 2 * S)] = cmulm(y2, c2, s2);
        L[swz(p + 3 * S)] = cmulm(y3, c3, s3);
        L[swz(p + 4 * S)] = cmulm(y4, c4, s4);
        L[swz(p + 5 * S)] = cmulm(y5, c5, s5);
        L[swz(p + 6 * S)] = cmulm(y6, c6, s6);
        L[swz(p + 7 * S)] = cmulm(y7, c7, s7);
    }
}

// first fwd stage (S=2048), zero-padded input: u4..u7 = 0
__device__ __forceinline__ void fwd8_first(v2f* L, int q,
                                           v2f u0, v2f u1, v2f u2, v2f u3)
{
    v2f e0 = u0 + u2, e1 = u0 - u2;
    v2f f0 = u1 + u3, f1 = u1 - u3;
    v2f y0 = e0 + f0, y4 = e0 - f0;
    v2f nf1 = mni(f1);
    v2f y2 = e1 + nf1, y6 = e1 - nf1;
    v2f v1 = cmulm(u1,  RSQ2, RSQ2);
    v2f v2 = mni(u2);
    v2f v3 = cmulm(u3, -RSQ2, RSQ2);
    v2f g0 = u0 + v2, g1 = u0 - v2;
    v2f h0 = v1 + v3, h1 = v1 - v3;
    v2f y1 = g0 + h0, y5 = g0 - h0;
    v2f nh1 = mni(h1);
    v2f y3 = g1 + nh1, y7 = g1 - nh1;
    float th = (float)q * (PI_F / 8192.0f);
    TWCHAIN7(th);
    L[swz(q)]         = y0;
    L[swz(q + 2048)]  = cmulm(y1, c1, s1);
    L[swz(q + 4096)]  = cmulm(y2, c2, s2);
    L[swz(q + 6144)]  = cmulm(y3, c3, s3);
    L[swz(q + 8192)]  = cmulm(y4, c4, s4);
    L[swz(q + 10240)] = cmulm(y5, c5, s5);
    L[swz(q + 12288)] = cmulm(y6, c6, s6);
    L[swz(q + 14336)] = cmulm(y7, c7, s7);
}

// ---- inverse radix-8 DIT stage (packed) -----------------------------------
template<int SH>
__device__ __forceinline__ void inv8_stage(v2f* L, int t)
{
    __syncthreads();
    const int S = 1 << SH;
#pragma unroll 1
    for (int m = 0; m < 2; ++m) {
        int b = t + (m << 10);
        int q = b & (S - 1);
        int p = ((b >> SH) << (SH + 3)) + q;
        float th = (float)q * (PI_F / (4.0f * (float)S));
        TWCHAIN7(th);
        v2f y0 = L[swz(p)];
        v2f y1 = cmulp(L[swz(p + S)],     c1, s1);
        v2f y2 = cmulp(L[swz(p + 2*S)],   c2, s2);
        v2f y3 = cmulp(L[swz(p + 3*S)],   c3, s3);
        v2f y4 = cmulp(L[swz(p + 4*S)],   c4, s4);
        v2f y5 = cmulp(L[swz(p + 5*S)],   c5, s5);
        v2f y6 = cmulp(L[swz(p + 6*S)],   c6, s6);
        v2f y7 = cmulp(L[swz(p + 7*S)],   c7, s7);
        v2f E0 = y0 + y4, F0 = y0 - y4;
        v2f E1 = y2 + y6, F1 = pli(y2 - y6);
        v2f a0 = E0 + E1, a2 = E0 - E1;
        v2f a1 = F0 + F1, a3 = F0 - F1;
        v2f G0 = y1 + y5, H0 = y1 - y5;
        v2f G1 = y3 + y7, H1 = pli(y3 - y7);
        v2f w0 = G0 + G1, w2 = G0 - G1;
        v2f w1 = H0 + H1, w3 = H0 - H1;
        v2f b0 = w0;
        v2f b1 = cmulp(w1,  RSQ2, RSQ2);
        v2f b2 = pli(w2);
        v2f b3 = cmulp(w3, -RSQ2, RSQ2);
        L[swz(p)]         = a0 + b0;
        L[swz(p + S)]     = a1 + b1;
        L[swz(p + 2 * S)] = a2 + b2;
        L[swz(p + 3 * S)] = a3 + b3;
        L[swz(p + 4 * S)] = a0 - b0;
        L[swz(p + 5 * S)] = a1 - b1;
        L[swz(p + 6 * S)] = a2 - b2;
        L[swz(p + 7 * S)] = a3 - b3;
    }
}

// trivial-twiddle radix-4 (S=1) fwd / inv (packed)
__device__ __forceinline__ void bf4f0(v2f& a, v2f& b, v2f& c, v2f& d)
{
    v2f A = a + c, B = a - c, C = b + d, D = mni(b - d);
    a = A + C; b = B + D; c = A - C; d = B - D;
}
__device__ __forceinline__ void bf4i0(v2f& a, v2f& b, v2f& c, v2f& d)
{
    v2f e0 = a + c, e1 = a - c, f0 = b + d, f1 = pli(b - d);
    a = e0 + f0; b = e1 + f1; c = e0 - f0; d = e1 - f1;
}

// ---------- Kernel 1: MLP hidden states h2[FO][LSEQ] ----------------------
__global__ void hidden_kernel(const float* __restrict__ W0, const float* __restrict__ b0,
                              const float* __restrict__ W1, const float* __restrict__ b1,
                              const float* __restrict__ W2, const float* __restrict__ b2,
                              const float* __restrict__ freq, float* __restrict__ hws)
{
    const int lane = threadIdx.x & 63;
    const int p = blockIdx.x * (blockDim.x >> 6) + (threadIdx.x >> 6);
    if (p >= LSEQ) return;
    const float tt = (float)p / (float)(LSEQ - 1);
    const float w  = 6.283185307179586f * (float)p / (float)LSEQ;

    float acc = b0[lane] + tt * W0[lane];
#pragma unroll
    for (int j = 0; j < BANDS; ++j) {
        float f = 1e-4f + (float)j * ((15.0f - 1e-4f) / 15.0f);
        float a = f * w;
        acc += __cosf(a)  * W0[(1 + j) * FO + lane];
        acc += -__sinf(a) * W0[(1 + BANDS + j) * FO + lane];
    }
    float h = __sinf(freq[lane] * acc);

    acc = b1[lane];
#pragma unroll
    for (int e = 0; e < FO; ++e) acc += __shfl(h, e) * W1[e * FO + lane];
    float h1 = __sinf(freq[lane] * acc);

    acc = b2[lane];
#pragma unroll
    for (int e = 0; e < FO; ++e) acc += __shfl(h1, e) * W2[e * FO + lane];
    float h2 = __sinf(freq[lane] * acc);

    hws[lane * LSEQ + p] = h2;
}

// ---------- Kernel 2: k[d][p] = (h2 . Wf) * (exp(-t|delta|)+0.05) ---------
#define DCHUNK 96
__global__ __launch_bounds__(256)
void filter_kernel(const float* __restrict__ hws, const float* __restrict__ Wf,
                   float* __restrict__ kws)
{
    __shared__ float hsh[FO][257];
    const int tid = threadIdx.x;
    const int p  = blockIdx.x * 256 + tid;
    const int d0 = blockIdx.y * DCHUNK;
#pragma unroll 1
    for (int j = 0; j < FO; ++j) hsh[j][tid] = hws[j * LSEQ + p];
    __syncthreads();
    const float tt = (float)p / (float)(LSEQ - 1);
    const float min_decay = -3.0701134573253937f;
    const float max_decay = -15.350567286626971f;
#pragma unroll 1
    for (int c = 0; c < DCHUNK / 32; ++c) {
        const int dc = d0 + c * 32;
#define DEFA(I) float a##I = 0.f;
        REP32(DEFA)
#undef DEFA
#pragma unroll 4
        for (int j = 0; j < FO; ++j) {
            float hj = hsh[j][tid];
            const float* Wj = Wf + j * DIMC + dc;
#define FMA_(I) a##I = fmaf(hj, Wj[I], a##I);
            REP32(FMA_)
#undef FMA_
        }
#define ST_(I) { int d = dc + I; \
    float delta = min_decay + (max_decay - min_decay) * ((float)d / (float)(DIMC - 1)); \
    float dec = __expf(-tt * fabsf(delta)); \
    kws[(size_t)d * LSEQ + p] = a##I * (dec + 0.05f); }
        REP32(ST_)
#undef ST_
    }
}

// ---------- Kernel 3: K-hat for TWO real channels per complex FFT ---------
template<int MODE>
__global__ __launch_bounds__(1024)
void kfft_kernel(const float* __restrict__ kf, const float* __restrict__ bias,
                 __half2* __restrict__ KF, float* __restrict__ outbase)
{
    __shared__ v2f L[NF];
    const int g = blockIdx.x, t = threadIdx.x;
    const int da = 2 * g, db = 2 * g + 1;
    const float* ka = kf + (size_t)da * LSEQ;
    const float* kb = kf + (size_t)db * LSEQ;
#pragma unroll 1
    for (int m = 0; m < 2; ++m) {
        int q = t + (m << 10);
        float vr = ka[q], vi = kb[q];
        if (q == 0) { vr += bias[da]; vi += bias[db]; }
        fwd8_first(L, q, (v2f){vr, vi},
                   (v2f){ka[q + 2048], kb[q + 2048]},
                   (v2f){ka[q + 4096], kb[q + 4096]},
                   (v2f){ka[q + 6144], kb[q + 6144]});
    }
    fwd8_stage<8>(L, t);   // S=256
    fwd8_stage<5>(L, t);   // S=32
    fwd8_stage<2>(L, t);   // S=4
    __syncthreads();
#pragma unroll 1
    for (int ch = 0; ch < 2; ++ch) {
        int n0 = (t << 4) + (ch << 3);
        v2f z0 = L[swz(n0)],     z1 = L[swz(n0 + 1)];
        v2f z2 = L[swz(n0 + 2)], z3 = L[swz(n0 + 3)];
        v2f z4 = L[swz(n0 + 4)], z5 = L[swz(n0 + 5)];
        v2f z6 = L[swz(n0 + 6)], z7 = L[swz(n0 + 7)];
        bf4f0(z0, z1, z2, z3); bf4f0(z4, z5, z6, z7);
        L[swz(n0)]     = z0; L[swz(n0 + 1)] = z1;
        L[swz(n0 + 2)] = z2; L[swz(n0 + 3)] = z3;
        L[swz(n0 + 4)] = z4; L[swz(n0 + 5)] = z5;
        L[swz(n0 + 6)] = z6; L[swz(n0 + 7)] = z7;
    }
    // Hermitian unpack + half2 store (1/N folded here, the ONLY scaling)
    __syncthreads();
    const float hn = 0.5f / 16384.f;
#pragma unroll 1
    for (int i = 0; i < 16; ++i) {
        int s = (i << 10) + t;
        int D0 = s >> 11, D1 = (s >> 8) & 7, D2 = (s >> 5) & 7, D3 = (s >> 2) & 7, E = s & 3;
        int n  = D0 + (D1 << 3) + (D2 << 6) + (D3 << 9) + (E << 12);
        int np = (16384 - n) & 16383;
        int sp = ((np & 7) << 11) | (((np >> 3) & 7) << 8) | (((np >> 6) & 7) << 5)
               | (((np >> 9) & 7) << 2) | ((np >> 12) & 3);
        v2f Zs = L[swz(s)];
        v2f Zp = L[swz(sp)];
        float kar = (Zs.x + Zp.x) * hn, kai = (Zs.y - Zp.y) * hn;
        float kbr = (Zs.y + Zp.y) * hn, kbi = (Zp.x - Zs.x) * hn;
        if (MODE == 0) {
            KF[(size_t)da * NF + s] = __floats2half2_rn(kar, kai);
            KF[(size_t)db * NF + s] = __floats2half2_rn(kbr, kbi);
        } else {
            __half2* Ha = (s < 8192)
                ? (__half2*)(outbase + (size_t)da * LSEQ) + s
                : (__half2*)(outbase + (size_t)(DIMC + da) * LSEQ) + (s - 8192);
            __half2* Hb = (s < 8192)
                ? (__half2*)(outbase + (size_t)db * LSEQ) + s
                : (__half2*)(outbase + (size_t)(DIMC + db) * LSEQ) + (s - 8192);
            *Ha = __floats2half2_rn(kar, kai);
            *Hb = __floats2half2_rn(kbr, kbi);
        }
    }
}

// ---------- Kernel 4: conv — fwd FFT(x packed), K-mult, inv FFT -----------
template<int MODE>
__global__ __launch_bounds__(1024)
void conv_kernel(const float* __restrict__ x, const __half2* __restrict__ KF,
                 float* __restrict__ out)
{
    __shared__ v2f L[NF];
    const int d = blockIdx.x, t = threadIdx.x;
    const float* x0 = x + (size_t)d * LSEQ;
    const float* x1 = x + (size_t)(DIMC + d) * LSEQ;
    float* o0 = out + (size_t)d * LSEQ;
    float* o1 = out + (size_t)(DIMC + d) * LSEQ;
#pragma unroll 1
    for (int m = 0; m < 2; ++m) {
        int q = t + (m << 10);
        fwd8_first(L, q, (v2f){x0[q], x1[q]},
                   (v2f){x0[q + 2048], x1[q + 2048]},
                   (v2f){x0[q + 4096], x1[q + 4096]},
                   (v2f){x0[q + 6144], x1[q + 6144]});
    }
    fwd8_stage<8>(L, t);
    fwd8_stage<5>(L, t);
    fwd8_stage<2>(L, t);
    // fwd r4 S=1 + K-mult (half2) + inv r4 S=1
    __syncthreads();
#pragma unroll 1
    for (int ch = 0; ch < 2; ++ch) {
        int n0 = (t << 4) + (ch << 3);
        v2f z0 = L[swz(n0)],     z1 = L[swz(n0 + 1)];
        v2f z2 = L[swz(n0 + 2)], z3 = L[swz(n0 + 3)];
        v2f z4 = L[swz(n0 + 4)], z5 = L[swz(n0 + 5)];
        v2f z6 = L[swz(n0 + 6)], z7 = L[swz(n0 + 7)];
        bf4f0(z0, z1, z2, z3); bf4f0(z4, z5, z6, z7);
        const __half2* H;
        if (MODE == 0) H = KF + (size_t)d * NF + n0;
        else H = (n0 < 8192)
            ? (const __half2*)(out + (size_t)d * LSEQ) + n0
            : (const __half2*)(out + (size_t)(DIMC + d) * LSEQ) + (n0 - 8192);
        // z*k = k*z.x + (i*k)*z.y
#define KMH(Z, J) { float2 kk = __half22float2(H[J]); v2f k = {kk.x, kk.y}; \
    Z = k * Z.x + pli(k) * Z.y; }
        KMH(z0,0) KMH(z1,1) KMH(z2,2) KMH(z3,3) KMH(z4,4) KMH(z5,5) KMH(z6,6) KMH(z7,7)
#undef KMH
        bf4i0(z0, z1, z2, z3); bf4i0(z4, z5, z6, z7);
        L[swz(n0)]     = z0; L[swz(n0 + 1)] = z1;
        L[swz(n0 + 2)] = z2; L[swz(n0 + 3)] = z3;
        L[swz(n0 + 4)] = z4; L[swz(n0 + 5)] = z5;
        L[swz(n0 + 6)] = z6; L[swz(n0 + 7)] = z7;
    }
    inv8_stage<2>(L, t);
    inv8_stage<5>(L, t);
    inv8_stage<8>(L, t);
    // inv radix-8 S=2048, truncated (outputs n<8192) + global store
    __syncthreads();
#pragma unroll 1
    for (int m = 0; m < 2; ++m) {
        int q = t + (m << 10);
        float th = (float)q * (PI_F / 8192.0f);
        TWCHAIN7(th);
        v2f y0 = L[swz(q)];
        v2f y1 = cmulp(L[swz(q + 2048)],  c1, s1);
        v2f y2 = cmulp(L[swz(q + 4096)],  c2, s2);
        v2f y3 = cmulp(L[swz(q + 6144)],  c3, s3);
        v2f y4 = cmulp(L[swz(q + 8192)],  c4, s4);
        v2f y5 = cmulp(L[swz(q + 10240)], c5, s5);
        v2f y6 = cmulp(L[swz(q + 12288)], c6, s6);
        v2f y7 = cmulp(L[swz(q + 14336)], c7, s7);
        v2f E0 = y0 + y4, F0 = y0 - y4;
        v2f E1 = y2 + y6, F1 = pli(y2 - y6);
        v2f a0 = E0 + E1, a2 = E0 - E1;
        v2f a1 = F0 + F1, a3 = F0 - F1;
        v2f G0 = y1 + y5, H0 = y1 - y5;
        v2f G1 = y3 + y7, H1 = pli(y3 - y7);
        v2f w0 = G0 + G1, w2 = G0 - G1;
        v2f w1 = H0 + H1, w3 = H0 - H1;
        v2f b0 = w0;
        v2f b1 = cmulp(w1,  RSQ2, RSQ2);
        v2f b2 = pli(w2);
        v2f b3 = cmulp(w3, -RSQ2, RSQ2);
        v2f r0 = a0 + b0, r1 = a1 + b1, r2 = a2 + b2, r3 = a3 + b3;
        o0[q]        = r0.x;  o1[q]        = r0.y;
        o0[q + 2048] = r1.x;  o1[q + 2048] = r1.y;
        o0[q + 4096] = r2.x;  o1[q + 4096] = r2.y;
        o0[q + 6144] = r3.x;  o1[q + 6144] = r3.y;
    }
}

extern "C" void kernel_launch(void* const* d_in, const int* in_sizes, int n_in,
                              void* d_out, int out_size, void* d_ws, size_t ws_size,
                              hipStream_t stream)
{
    (void)in_sizes; (void)n_in; (void)out_size;
    const float* x    = (const float*)d_in[0];
    const float* W0   = (const float*)d_in[1];
    const float* b0   = (const float*)d_in[2];
    const float* W1   = (const float*)d_in[3];
    const float* b1   = (const float*)d_in[4];
    const float* W2   = (const float*)d_in[5];
    const float* b2   = (const float*)d_in[6];
    const float* Wf   = (const float*)d_in[7];
    const float* freq = (const float*)d_in[8];
    const float* bias = (const float*)d_in[9];
    float* out = (float*)d_out;

    float* hws = out;                            // h2 staged in out rows 0..63
    float* kws = out + (size_t)DIMC * LSEQ;      // k staged in out rows 768..1535

    hipLaunchKernelGGL(hidden_kernel, dim3(LSEQ / 4), dim3(256), 0, stream,
                       W0, b0, W1, b1, W2, b2, freq, hws);
    hipLaunchKernelGGL(filter_kernel, dim3(LSEQ / 256, DIMC / DCHUNK), dim3(256), 0, stream,
                       hws, Wf, kws);

    const size_t kbytes = (size_t)DIMC * NF * sizeof(__half2);   // 50 MB
    if (ws_size >= kbytes) {
        __half2* KF = (__half2*)d_ws;
        hipLaunchKernelGGL(kfft_kernel<0>, dim3(DIMC / 2), dim3(1024), 0, stream,
                           kws, bias, KF, nullptr);
        hipLaunchKernelGGL(conv_kernel<0>, dim3(DIMC), dim3(1024), 0, stream,
                           x, KF, out);
    } else {
        hipLaunchKernelGGL(kfft_kernel<1>, dim3(DIMC / 2), dim3(1024), 0, stream,
                           kws, bias, nullptr, out);
        hipLaunchKernelGGL(conv_kernel<1>, dim3(DIMC), dim3(1024), 0, stream,
                           x, nullptr, out);
    }
}